// Round 2
// baseline (601.127 us; speedup 1.0000x reference)
//
#include <hip/hip_runtime.h>
#include <hip/hip_bf16.h>

using bf16s = __hip_bfloat16;
typedef __bf16 bf16x8 __attribute__((ext_vector_type(8)));
typedef float f32x4 __attribute__((ext_vector_type(4)));

// ---------------- degree count ----------------
__global__ __launch_bounds__(256) void count_deg(const int* __restrict__ dst,
                                                 int* __restrict__ deg, int E) {
    int i = blockIdx.x * blockDim.x + threadIdx.x;
    int stride = gridDim.x * blockDim.x;
    for (; i < E; i += stride) atomicAdd(&deg[dst[i]], 1);
}

// ---------------- scan: per-256-chunk exclusive scan ----------------
__global__ __launch_bounds__(256) void scan_chunks(const int* __restrict__ deg,
                                                   int* __restrict__ part,   // rowptr used as partials
                                                   int* __restrict__ sums, int n) {
    __shared__ int lds[256];
    int tid = threadIdx.x;
    int i = blockIdx.x * 256 + tid;
    int v = (i < n) ? deg[i] : 0;
    lds[tid] = v;
    __syncthreads();
    for (int off = 1; off < 256; off <<= 1) {
        int x = (tid >= off) ? lds[tid - off] : 0;
        __syncthreads();
        lds[tid] += x;
        __syncthreads();
    }
    if (i < n) part[i] = lds[tid] - v;           // exclusive within chunk
    if (tid == 255) sums[blockIdx.x] = lds[255]; // chunk total
}

// ---------------- scan chunk sums (single block, m <= 512) ----------------
__global__ __launch_bounds__(512) void scan_sums(int* __restrict__ sums, int m) {
    __shared__ int lds[512];
    int tid = threadIdx.x;
    int v = (tid < m) ? sums[tid] : 0;
    lds[tid] = v;
    __syncthreads();
    for (int off = 1; off < 512; off <<= 1) {
        int x = (tid >= off) ? lds[tid - off] : 0;
        __syncthreads();
        lds[tid] += x;
        __syncthreads();
    }
    if (tid < m) sums[tid] = lds[tid] - v;       // exclusive across chunks
}

// ---------------- finalize rowptr, cursor, dinv ----------------
__global__ __launch_bounds__(256) void finalize(const int* __restrict__ sums,
                                                const int* __restrict__ deg,
                                                int* __restrict__ rowptr,
                                                int* __restrict__ cursor,
                                                float* __restrict__ dinv, int n, int E) {
    int i = blockIdx.x * blockDim.x + threadIdx.x;
    if (i < n) {
        int r = rowptr[i] + sums[i >> 8];
        rowptr[i] = r;
        cursor[i] = r;
        dinv[i] = rsqrtf((float)(deg[i] + 1));   // +1 = self loop
        if (i == 0) rowptr[n] = E;
    }
}

// ---------------- place edges into CSR ----------------
__global__ __launch_bounds__(256) void place(const int* __restrict__ src,
                                             const int* __restrict__ dst,
                                             int* __restrict__ cursor,
                                             int* __restrict__ csr, int E) {
    int i = blockIdx.x * blockDim.x + threadIdx.x;
    int stride = gridDim.x * blockDim.x;
    for (; i < E; i += stride) {
        int s = src[i];
        int d = dst[i];
        int p = atomicAdd(&cursor[d], 1);
        csr[p] = s;
    }
}

// ---- GEMM: out[N,64](bf16) = A[N,64] @ W[64,64](f32), fp32 acc, MFMA 16x16x32 ----
// A is float32 (AF32=true) or bf16 (AF32=false); converted to bf16 fragments.
template <bool AF32>
__global__ __launch_bounds__(256) void gemm64(const void* __restrict__ A_,
                                              const float* __restrict__ W,
                                              bf16s* __restrict__ out, int nrows) {
    int lane = threadIdx.x & 63;
    int wid = (blockIdx.x * blockDim.x + threadIdx.x) >> 6;
    int nwaves = (gridDim.x * blockDim.x) >> 6;
    int r = lane & 15;       // col-in-tile
    int q = lane >> 4;       // quad
    int kb = q * 8;

    // B fragments: 4 n-tiles x 2 k-halves. B[k][n]: n=lane&15, k=quad*8+j
    bf16x8 bfrag[4][2];
#pragma unroll
    for (int t = 0; t < 4; t++) {
#pragma unroll
        for (int h = 0; h < 2; h++) {
            bf16x8 b;
            int ncol = t * 16 + r;
            int k0 = h * 32 + kb;
#pragma unroll
            for (int j = 0; j < 8; j++) b[j] = (__bf16)W[(k0 + j) * 64 + ncol];
            bfrag[t][h] = b;
        }
    }

    int ntiles = nrows >> 4;  // nrows divisible by 16 (100000/16 = 6250)
    for (int tile = wid; tile < ntiles; tile += nwaves) {
        bf16x8 a0, a1;
        if (AF32) {
            const float* ap = (const float*)A_ + (size_t)(tile * 16 + r) * 64 + kb;
            f32x4 v0 = *reinterpret_cast<const f32x4*>(ap);
            f32x4 v1 = *reinterpret_cast<const f32x4*>(ap + 4);
            f32x4 v2 = *reinterpret_cast<const f32x4*>(ap + 32);
            f32x4 v3 = *reinterpret_cast<const f32x4*>(ap + 36);
#pragma unroll
            for (int j = 0; j < 4; j++) {
                a0[j] = (__bf16)v0[j]; a0[4 + j] = (__bf16)v1[j];
                a1[j] = (__bf16)v2[j]; a1[4 + j] = (__bf16)v3[j];
            }
        } else {
            const __bf16* ap = (const __bf16*)A_ + (size_t)(tile * 16 + r) * 64 + kb;
            a0 = *reinterpret_cast<const bf16x8*>(ap);        // k 0..31
            a1 = *reinterpret_cast<const bf16x8*>(ap + 32);   // k 32..63
        }
        f32x4 c[4];
#pragma unroll
        for (int t = 0; t < 4; t++) {
            f32x4 acc = {0.f, 0.f, 0.f, 0.f};
            acc = __builtin_amdgcn_mfma_f32_16x16x32_bf16(a0, bfrag[t][0], acc, 0, 0, 0);
            acc = __builtin_amdgcn_mfma_f32_16x16x32_bf16(a1, bfrag[t][1], acc, 0, 0, 0);
            c[t] = acc;
        }
        // C/D layout: col = lane&15, row = quad*4 + reg
#pragma unroll
        for (int t = 0; t < 4; t++) {
#pragma unroll
            for (int g = 0; g < 4; g++) {
                int row = tile * 16 + q * 4 + g;
                out[(size_t)row * 64 + t * 16 + r] = __float2bfloat16(c[t][g]);
            }
        }
    }
}

// ---------------- aggregate: one wave per node, lane = feature ----------------
// out = relu(dinv[v] * (sum_{e} dinv[s]*t[s] + dinv[v]*t[v]) + bias)
template <bool OUTF32>
__global__ __launch_bounds__(256) void aggregate(const bf16s* __restrict__ t,
                                                 const float* __restrict__ dinv,
                                                 const int* __restrict__ rowptr,
                                                 const int* __restrict__ csr,
                                                 const float* __restrict__ bias,
                                                 void* __restrict__ out_, int n) {
    int gid = blockIdx.x * blockDim.x + threadIdx.x;
    int v = gid >> 6;
    int lane = gid & 63;
    if (v >= n) return;
    float dv = dinv[v];
    float acc = dv * __bfloat162float(t[(size_t)v * 64 + lane]);   // self-loop term
    int beg = rowptr[v], end = rowptr[v + 1];
    for (int j = beg; j < end; j++) {
        int s = csr[j];
        acc = fmaf(dinv[s], __bfloat162float(t[(size_t)s * 64 + lane]), acc);
    }
    float o = fmaf(dv, acc, bias[lane]);
    o = fmaxf(o, 0.f);  // both layers are relu'd in the reference
    if (OUTF32)
        ((float*)out_)[(size_t)v * 64 + lane] = o;
    else
        ((bf16s*)out_)[(size_t)v * 64 + lane] = __float2bfloat16(o);
}

extern "C" void kernel_launch(void* const* d_in, const int* in_sizes, int n_in,
                              void* d_out, int out_size, void* d_ws, size_t ws_size,
                              hipStream_t stream) {
    const float* x  = (const float*)d_in[0];
    const int*   ei = (const int*)d_in[1];
    const float* W1 = (const float*)d_in[2];
    const float* b1 = (const float*)d_in[3];
    const float* W2 = (const float*)d_in[4];
    const float* b2 = (const float*)d_in[5];
    float* out = (float*)d_out;

    int n = in_sizes[0] / 64;   // 100000
    int E = in_sizes[1] / 2;    // 1600000
    const int* src = ei;
    const int* dst = ei + E;

    // workspace carve (all buffers written before read each call)
    char* w = (char*)d_ws;
    auto alloc = [&](size_t bytes) -> void* {
        void* p = (void*)w;
        w += (bytes + 255) & ~(size_t)255;
        return p;
    };
    int*   deg    = (int*)alloc((size_t)n * 4);
    int*   rowptr = (int*)alloc((size_t)(n + 1) * 4);
    int*   cursor = (int*)alloc((size_t)n * 4);
    int*   sums   = (int*)alloc(4096);
    int*   csr    = (int*)alloc((size_t)E * 4);
    float* dinv   = (float*)alloc((size_t)n * 4);
    bf16s* tbuf   = (bf16s*)alloc((size_t)n * 64 * 2);
    bf16s* h1     = (bf16s*)alloc((size_t)n * 64 * 2);

    hipMemsetAsync(deg, 0, (size_t)n * 4, stream);

    count_deg<<<1024, 256, 0, stream>>>(dst, deg, E);

    int nch = (n + 255) / 256;  // 391
    scan_chunks<<<nch, 256, 0, stream>>>(deg, rowptr, sums, n);
    scan_sums<<<1, 512, 0, stream>>>(sums, nch);
    finalize<<<(n + 255) / 256, 256, 0, stream>>>(sums, deg, rowptr, cursor, dinv, n, E);
    place<<<1024, 256, 0, stream>>>(src, dst, cursor, csr, E);

    // layer 1: t = bf16(x @ W1); h1 = relu(aggregate(t)) in bf16
    gemm64<true><<<256, 256, 0, stream>>>(x, W1, tbuf, n);
    aggregate<false><<<(n * 64 + 255) / 256, 256, 0, stream>>>(tbuf, dinv, rowptr, csr, b1, h1, n);
    // layer 2: t = bf16(h1 @ W2); out = relu(aggregate(t)) in fp32
    gemm64<false><<<256, 256, 0, stream>>>(h1, W2, tbuf, n);
    aggregate<true><<<(n * 64 + 255) / 256, 256, 0, stream>>>(tbuf, dinv, rowptr, csr, b2, out, n);
}

// Round 3
// 382.951 us; speedup vs baseline: 1.5697x; 1.5697x over previous
//
#include <hip/hip_runtime.h>
#include <hip/hip_bf16.h>

using bf16s = __hip_bfloat16;
typedef __bf16 bf16x8 __attribute__((ext_vector_type(8)));
typedef float f32x4 __attribute__((ext_vector_type(4)));

// ---------------- degree count ----------------
__global__ __launch_bounds__(256) void count_deg(const int* __restrict__ dst,
                                                 int* __restrict__ deg, int E) {
    int i = blockIdx.x * blockDim.x + threadIdx.x;
    int stride = gridDim.x * blockDim.x;
    for (; i < E; i += stride) atomicAdd(&deg[dst[i]], 1);
}

// ---------------- scan: per-256-chunk exclusive scan ----------------
__global__ __launch_bounds__(256) void scan_chunks(const int* __restrict__ deg,
                                                   int* __restrict__ part,   // rowptr used as partials
                                                   int* __restrict__ sums, int n) {
    __shared__ int lds[256];
    int tid = threadIdx.x;
    int i = blockIdx.x * 256 + tid;
    int v = (i < n) ? deg[i] : 0;
    lds[tid] = v;
    __syncthreads();
    for (int off = 1; off < 256; off <<= 1) {
        int x = (tid >= off) ? lds[tid - off] : 0;
        __syncthreads();
        lds[tid] += x;
        __syncthreads();
    }
    if (i < n) part[i] = lds[tid] - v;           // exclusive within chunk
    if (tid == 255) sums[blockIdx.x] = lds[255]; // chunk total
}

// ---------------- scan chunk sums (single block, m <= 512) ----------------
__global__ __launch_bounds__(512) void scan_sums(int* __restrict__ sums, int m) {
    __shared__ int lds[512];
    int tid = threadIdx.x;
    int v = (tid < m) ? sums[tid] : 0;
    lds[tid] = v;
    __syncthreads();
    for (int off = 1; off < 512; off <<= 1) {
        int x = (tid >= off) ? lds[tid - off] : 0;
        __syncthreads();
        lds[tid] += x;
        __syncthreads();
    }
    if (tid < m) sums[tid] = lds[tid] - v;       // exclusive across chunks
}

// ---------------- finalize rowptr, dinv ----------------
__global__ __launch_bounds__(256) void finalize(const int* __restrict__ sums,
                                                const int* __restrict__ deg,
                                                int* __restrict__ rowptr,
                                                float* __restrict__ dinv, int n, int E) {
    int i = blockIdx.x * blockDim.x + threadIdx.x;
    if (i < n) {
        int r = rowptr[i] + sums[i >> 8];
        rowptr[i] = r;
        dinv[i] = rsqrtf((float)(deg[i] + 1));   // +1 = self loop
        if (i == 0) rowptr[n] = E;
    }
}

// ---------------- init coarse-bucket cursors ----------------
__global__ __launch_bounds__(512) void init_gcur(const int* __restrict__ rowptr,
                                                 int* __restrict__ gcur, int nbuck) {
    int i = threadIdx.x;
    if (i < nbuck) gcur[i] = rowptr[i << 8];
}

// ---------------- multisplit: partition edges into 256-node coarse buckets ----
// Writes packed (src<<8 | dst&255) ints, bucket-contiguous per tile, coalesced.
constexpr int MS_TILE = 4096;
__global__ __launch_bounds__(256) void multisplit(const int* __restrict__ src,
                                                  const int* __restrict__ dst,
                                                  int* __restrict__ gcur,
                                                  int* __restrict__ part, int E) {
    __shared__ int cnt[512];
    __shared__ int off[512];
    __shared__ int gbase[512];
    __shared__ int img[MS_TILE];
    __shared__ int tgt[MS_TILE];
    int tid = threadIdx.x;
    for (int tbase = blockIdx.x * MS_TILE; tbase < E; tbase += gridDim.x * MS_TILE) {
        int m = min(MS_TILE, E - tbase);
        for (int i = tid; i < 512; i += 256) cnt[i] = 0;
        __syncthreads();
        int pk[16], bk[16], rk[16];
        int nloc = 0;
        for (int j = tid; j < m; j += 256) {
            int s = src[tbase + j];
            int d = dst[tbase + j];
            int b = d >> 8;
            pk[nloc] = (s << 8) | (d & 255);
            bk[nloc] = b;
            rk[nloc] = atomicAdd(&cnt[b], 1);
            nloc++;
        }
        __syncthreads();
        // exclusive scan of cnt[0..512) by wave 0 (64 lanes x 8 serial)
        if (tid < 64) {
            int base = tid * 8;
            int vals[8];
            int s0 = 0;
#pragma unroll
            for (int j = 0; j < 8; j++) { vals[j] = cnt[base + j]; s0 += vals[j]; }
            int sc = s0;
#pragma unroll
            for (int o = 1; o < 64; o <<= 1) {
                int u = __shfl_up(sc, o);
                if (tid >= o) sc += u;
            }
            int ex = sc - s0;
#pragma unroll
            for (int j = 0; j < 8; j++) { off[base + j] = ex; ex += vals[j]; }
        }
        __syncthreads();
        // reserve global space per bucket (one atomic per WG per nonempty bucket)
        for (int b = tid; b < 512; b += 256) {
            int c = cnt[b];
            gbase[b] = c ? atomicAdd(&gcur[b], c) : 0;
        }
        __syncthreads();
        // scatter into LDS, grouped by bucket
        for (int i = 0; i < nloc; i++) {
            int p = off[bk[i]] + rk[i];
            img[p] = pk[i];
            tgt[p] = gbase[bk[i]] + rk[i];
        }
        __syncthreads();
        // coalesced write-out (consecutive slots -> consecutive targets per bucket run)
        for (int j = tid; j < m; j += 256) part[tgt[j]] = img[j];
        __syncthreads();
    }
}

// ---------------- bucket_place: exact per-node CSR via LDS image ----------------
constexpr int PCAP = 8704;   // >> E[bucket]=4096, Poisson sigma=64
__global__ __launch_bounds__(256) void bucket_place(const int* __restrict__ rowptr,
                                                    const int* __restrict__ part,
                                                    int* __restrict__ csr, int n) {
    __shared__ int nodeCur[256];
    __shared__ int img[PCAP];
    int b = blockIdx.x;
    int node0 = b << 8;
    int nn = min(256, n - node0);
    int base = rowptr[node0];
    int end = rowptr[node0 + nn];
    int cnt = end - base;
    int tid = threadIdx.x;
    if (tid < nn) nodeCur[tid] = rowptr[node0 + tid] - base;
    __syncthreads();
    if (cnt <= PCAP) {
        for (int j = tid; j < cnt; j += 256) {
            int pk = part[base + j];
            int p = atomicAdd(&nodeCur[pk & 255], 1);
            img[p] = pk >> 8;
        }
        __syncthreads();
        for (int j = tid; j < cnt; j += 256) csr[base + j] = img[j];
    } else {  // safety fallback (statistically never)
        for (int j = tid; j < cnt; j += 256) {
            int pk = part[base + j];
            int p = atomicAdd(&nodeCur[pk & 255], 1);
            csr[base + p] = pk >> 8;
        }
    }
}

// ---- GEMM + dinv prescale: out[r] = bf16(dinv[r] * (A[r] @ W)), MFMA 16x16x32 ----
template <bool AF32>
__global__ __launch_bounds__(256) void gemm64(const void* __restrict__ A_,
                                              const float* __restrict__ W,
                                              const float* __restrict__ dinv,
                                              bf16s* __restrict__ out, int nrows) {
    int lane = threadIdx.x & 63;
    int wid = (blockIdx.x * blockDim.x + threadIdx.x) >> 6;
    int nwaves = (gridDim.x * blockDim.x) >> 6;
    int r = lane & 15;       // col-in-tile
    int q = lane >> 4;       // quad
    int kb = q * 8;

    // B fragments: 4 n-tiles x 2 k-halves. B[k][n]: n=lane&15, k=quad*8+j
    bf16x8 bfrag[4][2];
#pragma unroll
    for (int t = 0; t < 4; t++) {
#pragma unroll
        for (int h = 0; h < 2; h++) {
            bf16x8 b;
            int ncol = t * 16 + r;
            int k0 = h * 32 + kb;
#pragma unroll
            for (int j = 0; j < 8; j++) b[j] = (__bf16)W[(k0 + j) * 64 + ncol];
            bfrag[t][h] = b;
        }
    }

    int ntiles = nrows >> 4;
    for (int tile = wid; tile < ntiles; tile += nwaves) {
        bf16x8 a0, a1;
        if (AF32) {
            const float* ap = (const float*)A_ + (size_t)(tile * 16 + r) * 64 + kb;
            f32x4 v0 = *reinterpret_cast<const f32x4*>(ap);
            f32x4 v1 = *reinterpret_cast<const f32x4*>(ap + 4);
            f32x4 v2 = *reinterpret_cast<const f32x4*>(ap + 32);
            f32x4 v3 = *reinterpret_cast<const f32x4*>(ap + 36);
#pragma unroll
            for (int j = 0; j < 4; j++) {
                a0[j] = (__bf16)v0[j]; a0[4 + j] = (__bf16)v1[j];
                a1[j] = (__bf16)v2[j]; a1[4 + j] = (__bf16)v3[j];
            }
        } else {
            const __bf16* ap = (const __bf16*)A_ + (size_t)(tile * 16 + r) * 64 + kb;
            a0 = *reinterpret_cast<const bf16x8*>(ap);
            a1 = *reinterpret_cast<const bf16x8*>(ap + 32);
        }
        f32x4 c[4];
#pragma unroll
        for (int t = 0; t < 4; t++) {
            f32x4 acc = {0.f, 0.f, 0.f, 0.f};
            acc = __builtin_amdgcn_mfma_f32_16x16x32_bf16(a0, bfrag[t][0], acc, 0, 0, 0);
            acc = __builtin_amdgcn_mfma_f32_16x16x32_bf16(a1, bfrag[t][1], acc, 0, 0, 0);
            c[t] = acc;
        }
        // C/D layout: col = lane&15, row = quad*4 + reg
        float dr[4];
#pragma unroll
        for (int g = 0; g < 4; g++) dr[g] = dinv[tile * 16 + q * 4 + g];
#pragma unroll
        for (int t = 0; t < 4; t++) {
#pragma unroll
            for (int g = 0; g < 4; g++) {
                int row = tile * 16 + q * 4 + g;
                out[(size_t)row * 64 + t * 16 + r] = __float2bfloat16(c[t][g] * dr[g]);
            }
        }
    }
}

// ---------------- aggregate: one wave per node, lane = feature ----------------
// t is pre-scaled by dinv[src]: out = relu(dinv[v] * (sum_e t[s] + t[v]) + bias)
template <bool OUTF32>
__global__ __launch_bounds__(256) void aggregate(const bf16s* __restrict__ t,
                                                 const float* __restrict__ dinv,
                                                 const int* __restrict__ rowptr,
                                                 const int* __restrict__ csr,
                                                 const float* __restrict__ bias,
                                                 void* __restrict__ out_, int n) {
    int gid = blockIdx.x * blockDim.x + threadIdx.x;
    int v = gid >> 6;
    int lane = gid & 63;
    if (v >= n) return;
    float acc = __bfloat162float(t[(size_t)v * 64 + lane]);   // self-loop: dinv[v]*t_raw[v]
    int beg = rowptr[v], end = rowptr[v + 1];
    int j = beg;
    for (; j + 2 <= end; j += 2) {
        int s0 = csr[j], s1 = csr[j + 1];
        float u0 = __bfloat162float(t[(size_t)s0 * 64 + lane]);
        float u1 = __bfloat162float(t[(size_t)s1 * 64 + lane]);
        acc += u0 + u1;
    }
    if (j < end) acc += __bfloat162float(t[(size_t)csr[j] * 64 + lane]);
    float o = fmaf(dinv[v], acc, bias[lane]);
    o = fmaxf(o, 0.f);
    if (OUTF32)
        ((float*)out_)[(size_t)v * 64 + lane] = o;
    else
        ((bf16s*)out_)[(size_t)v * 64 + lane] = __float2bfloat16(o);
}

extern "C" void kernel_launch(void* const* d_in, const int* in_sizes, int n_in,
                              void* d_out, int out_size, void* d_ws, size_t ws_size,
                              hipStream_t stream) {
    const float* x  = (const float*)d_in[0];
    const int*   ei = (const int*)d_in[1];
    const float* W1 = (const float*)d_in[2];
    const float* b1 = (const float*)d_in[3];
    const float* W2 = (const float*)d_in[4];
    const float* b2 = (const float*)d_in[5];
    float* out = (float*)d_out;

    int n = in_sizes[0] / 64;   // 100000
    int E = in_sizes[1] / 2;    // 1600000
    const int* src = ei;
    const int* dst = ei + E;
    int nbuck = (n + 255) >> 8; // 391

    // workspace carve
    char* w = (char*)d_ws;
    auto alloc = [&](size_t bytes) -> void* {
        void* p = (void*)w;
        w += (bytes + 255) & ~(size_t)255;
        return p;
    };
    int*   deg    = (int*)alloc((size_t)n * 4);
    int*   rowptr = (int*)alloc((size_t)(n + 1) * 4);
    int*   sums   = (int*)alloc(4096);
    int*   gcur   = (int*)alloc(2048);
    int*   csr    = (int*)alloc((size_t)E * 4);
    float* dinv   = (float*)alloc((size_t)n * 4);
    // overlay: part (E ints) shares space with tbuf (n*64 bf16) — part is dead
    // after bucket_place, before the first gemm writes tbuf.
    char*  ovl    = (char*)alloc((size_t)n * 64 * 2 > (size_t)E * 4 ? (size_t)n * 64 * 2
                                                                    : (size_t)E * 4);
    int*   part   = (int*)ovl;
    bf16s* tbuf   = (bf16s*)ovl;
    bf16s* h1     = (bf16s*)alloc((size_t)n * 64 * 2);

    hipMemsetAsync(deg, 0, (size_t)n * 4, stream);
    count_deg<<<1024, 256, 0, stream>>>(dst, deg, E);

    int nch = (n + 255) / 256;
    scan_chunks<<<nch, 256, 0, stream>>>(deg, rowptr, sums, n);
    scan_sums<<<1, 512, 0, stream>>>(sums, nch);
    finalize<<<(n + 255) / 256, 256, 0, stream>>>(sums, deg, rowptr, dinv, n, E);
    init_gcur<<<1, 512, 0, stream>>>(rowptr, gcur, nbuck);

    int ntiles = (E + MS_TILE - 1) / MS_TILE;
    multisplit<<<ntiles, 256, 0, stream>>>(src, dst, gcur, part, E);
    bucket_place<<<nbuck, 256, 0, stream>>>(rowptr, part, csr, n);

    // layer 1: t = bf16(dinv .* (x @ W1)); h1 = relu(aggregate) in bf16
    gemm64<true><<<256, 256, 0, stream>>>(x, W1, dinv, tbuf, n);
    aggregate<false><<<(n * 64 + 255) / 256, 256, 0, stream>>>(tbuf, dinv, rowptr, csr, b1, h1, n);
    // layer 2: t = bf16(dinv .* (h1 @ W2)); out = relu(aggregate) in fp32
    gemm64<false><<<256, 256, 0, stream>>>(h1, W2, dinv, tbuf, n);
    aggregate<true><<<(n * 64 + 255) / 256, 256, 0, stream>>>(tbuf, dinv, rowptr, csr, b2, out, n);
}

// Round 4
// 258.397 us; speedup vs baseline: 2.3264x; 1.4820x over previous
//
#include <hip/hip_runtime.h>
#include <hip/hip_bf16.h>

using bf16s = __hip_bfloat16;
typedef __bf16 bf16x8 __attribute__((ext_vector_type(8)));
typedef float f32x4 __attribute__((ext_vector_type(4)));

constexpr int MS_TILE = 2048;

// ---------------- bucket histogram (391 coarse buckets of 256 nodes) ----------------
__global__ __launch_bounds__(256) void bucket_count(const int* __restrict__ dst,
                                                    int* __restrict__ bcnt, int E) {
    __shared__ int h[512];
    int tid = threadIdx.x;
    for (int i = tid; i < 512; i += 256) h[i] = 0;
    __syncthreads();
    int i = blockIdx.x * blockDim.x + tid;
    int stride = gridDim.x * blockDim.x;
    for (; i < E; i += stride) atomicAdd(&h[dst[i] >> 8], 1);
    __syncthreads();
    for (int b = tid; b < 512; b += 256)
        if (h[b]) atomicAdd(&bcnt[b], h[b]);
}

// ---------------- scan bucket counts -> bases (in place) + cursor copy ----------------
__global__ __launch_bounds__(512) void scan_bases(int* __restrict__ bcnt,
                                                  int* __restrict__ gcur, int m, int E) {
    __shared__ int lds[512];
    int tid = threadIdx.x;
    int v = (tid < m) ? bcnt[tid] : 0;
    lds[tid] = v;
    __syncthreads();
    for (int off = 1; off < 512; off <<= 1) {
        int x = (tid >= off) ? lds[tid - off] : 0;
        __syncthreads();
        lds[tid] += x;
        __syncthreads();
    }
    int ex = lds[tid] - v;   // exclusive
    if (tid <= m) {
        bcnt[tid] = ex;      // bcnt[m] == E
        gcur[tid] = ex;
    }
}

// ---------------- multisplit: partition edges into coarse buckets ----------------
// Writes packed (src<<8 | dst&255) ints, bucket-contiguous per tile, coalesced.
__global__ __launch_bounds__(256) void multisplit(const int* __restrict__ src,
                                                  const int* __restrict__ dst,
                                                  int* __restrict__ gcur,
                                                  int* __restrict__ part, int E) {
    __shared__ int cnt[512];
    __shared__ int off[512];
    __shared__ int gbase[512];
    __shared__ int img[MS_TILE];
    __shared__ int tgt[MS_TILE];
    int tid = threadIdx.x;
    for (int tbase = blockIdx.x * MS_TILE; tbase < E; tbase += gridDim.x * MS_TILE) {
        int m = min(MS_TILE, E - tbase);
        for (int i = tid; i < 512; i += 256) cnt[i] = 0;
        __syncthreads();
        int pk[8], bk[8], rk[8];
        int nloc = 0;
        for (int j = tid; j < m; j += 256) {
            int s = src[tbase + j];
            int d = dst[tbase + j];
            int b = d >> 8;
            pk[nloc] = (s << 8) | (d & 255);
            bk[nloc] = b;
            rk[nloc] = atomicAdd(&cnt[b], 1);
            nloc++;
        }
        __syncthreads();
        // exclusive scan of cnt[0..512) by wave 0 (64 lanes x 8 serial)
        if (tid < 64) {
            int base = tid * 8;
            int vals[8];
            int s0 = 0;
#pragma unroll
            for (int j = 0; j < 8; j++) { vals[j] = cnt[base + j]; s0 += vals[j]; }
            int sc = s0;
#pragma unroll
            for (int o = 1; o < 64; o <<= 1) {
                int u = __shfl_up(sc, o);
                if (tid >= o) sc += u;
            }
            int ex = sc - s0;
#pragma unroll
            for (int j = 0; j < 8; j++) { off[base + j] = ex; ex += vals[j]; }
        }
        __syncthreads();
        // reserve global space per bucket (one atomic per WG per nonempty bucket)
        for (int b = tid; b < 512; b += 256) {
            int c = cnt[b];
            gbase[b] = c ? atomicAdd(&gcur[b], c) : 0;
        }
        __syncthreads();
        // scatter into LDS, grouped by bucket
        for (int i = 0; i < nloc; i++) {
            int p = off[bk[i]] + rk[i];
            img[p] = pk[i];
            tgt[p] = gbase[bk[i]] + rk[i];
        }
        __syncthreads();
        // coalesced write-out (consecutive slots -> consecutive targets per bucket run)
        for (int j = tid; j < m; j += 256) part[tgt[j]] = img[j];
        __syncthreads();
    }
}

// ------- bucket_place: per-node rowptr/dinv/CSR from the bucket's packed edges -------
__global__ __launch_bounds__(256) void bucket_place(const int* __restrict__ bbase,
                                                    const int* __restrict__ part,
                                                    int* __restrict__ rowptr,
                                                    int* __restrict__ csr,
                                                    float* __restrict__ dinv, int n) {
    __shared__ int cnt[256];
    __shared__ int cur[256];
    __shared__ int lds[256];
    int b = blockIdx.x;
    int tid = threadIdx.x;
    int node0 = b << 8;
    int base = bbase[b], end = bbase[b + 1];
    int m = end - base;
    cnt[tid] = 0;
    __syncthreads();
    for (int j = tid; j < m; j += 256) atomicAdd(&cnt[part[base + j] & 255], 1);
    __syncthreads();
    int v = cnt[tid];
    lds[tid] = v;
    __syncthreads();
    for (int off = 1; off < 256; off <<= 1) {
        int x = (tid >= off) ? lds[tid - off] : 0;
        __syncthreads();
        lds[tid] += x;
        __syncthreads();
    }
    int ex = lds[tid] - v;   // exclusive within bucket
    cur[tid] = ex;
    int node = node0 + tid;
    if (node <= n) rowptr[node] = base + ex;   // last bucket's tid==n-node0 writes rowptr[n]=E
    if (node < n) dinv[node] = rsqrtf((float)(v + 1));  // +1 = self loop
    __syncthreads();
    for (int j = tid; j < m; j += 256) {
        int pk = part[base + j];
        int p = atomicAdd(&cur[pk & 255], 1);
        csr[base + p] = pk >> 8;   // scattered, but within this WG's private 16KB window
    }
}

// ---- GEMM + dinv prescale: out[r] = bf16(dinv[r] * (A[r] @ W)), MFMA 16x16x32 ----
template <bool AF32>
__global__ __launch_bounds__(256) void gemm64(const void* __restrict__ A_,
                                              const float* __restrict__ W,
                                              const float* __restrict__ dinv,
                                              bf16s* __restrict__ out, int nrows) {
    int lane = threadIdx.x & 63;
    int wid = (blockIdx.x * blockDim.x + threadIdx.x) >> 6;
    int nwaves = (gridDim.x * blockDim.x) >> 6;
    int r = lane & 15;       // col-in-tile
    int q = lane >> 4;       // quad
    int kb = q * 8;

    // B fragments: 4 n-tiles x 2 k-halves. B[k][n]: n=lane&15, k=quad*8+j
    bf16x8 bfrag[4][2];
#pragma unroll
    for (int t = 0; t < 4; t++) {
#pragma unroll
        for (int h = 0; h < 2; h++) {
            bf16x8 bb;
            int ncol = t * 16 + r;
            int k0 = h * 32 + kb;
#pragma unroll
            for (int j = 0; j < 8; j++) bb[j] = (__bf16)W[(k0 + j) * 64 + ncol];
            bfrag[t][h] = bb;
        }
    }

    int ntiles = nrows >> 4;
    for (int tile = wid; tile < ntiles; tile += nwaves) {
        bf16x8 a0, a1;
        if (AF32) {
            const float* ap = (const float*)A_ + (size_t)(tile * 16 + r) * 64 + kb;
            f32x4 v0 = *reinterpret_cast<const f32x4*>(ap);
            f32x4 v1 = *reinterpret_cast<const f32x4*>(ap + 4);
            f32x4 v2 = *reinterpret_cast<const f32x4*>(ap + 32);
            f32x4 v3 = *reinterpret_cast<const f32x4*>(ap + 36);
#pragma unroll
            for (int j = 0; j < 4; j++) {
                a0[j] = (__bf16)v0[j]; a0[4 + j] = (__bf16)v1[j];
                a1[j] = (__bf16)v2[j]; a1[4 + j] = (__bf16)v3[j];
            }
        } else {
            const __bf16* ap = (const __bf16*)A_ + (size_t)(tile * 16 + r) * 64 + kb;
            a0 = *reinterpret_cast<const bf16x8*>(ap);
            a1 = *reinterpret_cast<const bf16x8*>(ap + 32);
        }
        f32x4 c[4];
#pragma unroll
        for (int t = 0; t < 4; t++) {
            f32x4 acc = {0.f, 0.f, 0.f, 0.f};
            acc = __builtin_amdgcn_mfma_f32_16x16x32_bf16(a0, bfrag[t][0], acc, 0, 0, 0);
            acc = __builtin_amdgcn_mfma_f32_16x16x32_bf16(a1, bfrag[t][1], acc, 0, 0, 0);
            c[t] = acc;
        }
        // C/D layout: col = lane&15, row = quad*4 + reg
        float dr[4];
#pragma unroll
        for (int g = 0; g < 4; g++) dr[g] = dinv[tile * 16 + q * 4 + g];
#pragma unroll
        for (int t = 0; t < 4; t++) {
#pragma unroll
            for (int g = 0; g < 4; g++) {
                int row = tile * 16 + q * 4 + g;
                out[(size_t)row * 64 + t * 16 + r] = __float2bfloat16(c[t][g] * dr[g]);
            }
        }
    }
}

// ---------------- aggregate: one wave per node, lane = feature, 8 gathers in flight ----
// t is pre-scaled by dinv[src]: out = relu(dinv[v] * (sum_e t[s] + t[v]) + bias)
template <bool OUTF32>
__global__ __launch_bounds__(256) void aggregate(const bf16s* __restrict__ t,
                                                 const float* __restrict__ dinv,
                                                 const int* __restrict__ rowptr,
                                                 const int* __restrict__ csr,
                                                 const float* __restrict__ bias,
                                                 void* __restrict__ out_, int n) {
    int gid = blockIdx.x * blockDim.x + threadIdx.x;
    int v = gid >> 6;
    int lane = gid & 63;
    if (v >= n) return;
    int beg = rowptr[v], end = rowptr[v + 1];
    float acc = __bfloat162float(t[(size_t)v * 64 + lane]);   // self-loop: dinv[v]*t_raw[v]
    for (int j = beg; j < end; j += 8) {
        int idx[8];
        float wgt[8];
#pragma unroll
        for (int k = 0; k < 8; k++) {
            int jj = j + k;
            bool ok = jj < end;
            idx[k] = csr[ok ? jj : beg];   // beg always valid when loop runs
            wgt[k] = ok ? 1.f : 0.f;
        }
        float u[8];
#pragma unroll
        for (int k = 0; k < 8; k++) u[k] = __bfloat162float(t[(size_t)idx[k] * 64 + lane]);
#pragma unroll
        for (int k = 0; k < 8; k++) acc = fmaf(wgt[k], u[k], acc);
    }
    float o = fmaf(dinv[v], acc, bias[lane]);
    o = fmaxf(o, 0.f);
    if (OUTF32)
        ((float*)out_)[(size_t)v * 64 + lane] = o;
    else
        ((bf16s*)out_)[(size_t)v * 64 + lane] = __float2bfloat16(o);
}

extern "C" void kernel_launch(void* const* d_in, const int* in_sizes, int n_in,
                              void* d_out, int out_size, void* d_ws, size_t ws_size,
                              hipStream_t stream) {
    const float* x  = (const float*)d_in[0];
    const int*   ei = (const int*)d_in[1];
    const float* W1 = (const float*)d_in[2];
    const float* b1 = (const float*)d_in[3];
    const float* W2 = (const float*)d_in[4];
    const float* b2 = (const float*)d_in[5];
    float* out = (float*)d_out;

    int n = in_sizes[0] / 64;   // 100000
    int E = in_sizes[1] / 2;    // 1600000
    const int* src = ei;
    const int* dst = ei + E;
    int nbuck = (n + 255) >> 8; // 391

    // workspace carve
    char* w = (char*)d_ws;
    auto alloc = [&](size_t bytes) -> void* {
        void* p = (void*)w;
        w += (bytes + 255) & ~(size_t)255;
        return p;
    };
    int*   bcnt   = (int*)alloc(2048);                  // bucket counts -> bases
    int*   gcur   = (int*)alloc(2048);
    int*   rowptr = (int*)alloc((size_t)(n + 1) * 4);
    int*   csr    = (int*)alloc((size_t)E * 4);
    float* dinv   = (float*)alloc((size_t)n * 4);
    // overlay: part (E ints) shares space with tbuf (n*64 bf16) — part is dead
    // after bucket_place, before the first gemm writes tbuf.
    char*  ovl    = (char*)alloc((size_t)n * 64 * 2 > (size_t)E * 4 ? (size_t)n * 64 * 2
                                                                    : (size_t)E * 4);
    int*   part   = (int*)ovl;
    bf16s* tbuf   = (bf16s*)ovl;
    bf16s* h1     = (bf16s*)alloc((size_t)n * 64 * 2);

    hipMemsetAsync(bcnt, 0, 2048, stream);
    bucket_count<<<256, 256, 0, stream>>>(dst, bcnt, E);
    scan_bases<<<1, 512, 0, stream>>>(bcnt, gcur, nbuck, E);

    int ntiles = (E + MS_TILE - 1) / MS_TILE;   // 782
    multisplit<<<ntiles, 256, 0, stream>>>(src, dst, gcur, part, E);
    bucket_place<<<nbuck, 256, 0, stream>>>(bcnt, part, rowptr, csr, dinv, n);

    // layer 1: t = bf16(dinv .* (x @ W1)); h1 = relu(aggregate) in bf16
    gemm64<true><<<256, 256, 0, stream>>>(x, W1, dinv, tbuf, n);
    aggregate<false><<<(n * 64 + 255) / 256, 256, 0, stream>>>(tbuf, dinv, rowptr, csr, b1, h1, n);
    // layer 2: t = bf16(dinv .* (h1 @ W2)); out = relu(aggregate) in fp32
    gemm64<false><<<256, 256, 0, stream>>>(h1, W2, dinv, tbuf, n);
    aggregate<true><<<(n * 64 + 255) / 256, 256, 0, stream>>>(tbuf, dinv, rowptr, csr, b2, out, n);
}

// Round 5
// 232.037 us; speedup vs baseline: 2.5906x; 1.1136x over previous
//
#include <hip/hip_runtime.h>
#include <hip/hip_bf16.h>

using bf16s = __hip_bfloat16;
typedef __bf16 bf16x8 __attribute__((ext_vector_type(8)));
typedef float f32x4 __attribute__((ext_vector_type(4)));

constexpr int MS_TILE = 2048;
constexpr int SLAB_CAP = 5120;   // avg bucket fill = 4092, sigma = 64 -> 16 sigma slack

// ---------------- multisplit: partition edges into 256-node coarse bucket slabs ----
// Appends packed (src<<8 | dst&255) ints into slab b*SLAB_CAP, coalesced runs.
__global__ __launch_bounds__(256) void multisplit(const int* __restrict__ src,
                                                  const int* __restrict__ dst,
                                                  int* __restrict__ gcur,
                                                  int* __restrict__ part, int E) {
    __shared__ int cnt[512];
    __shared__ int off[512];
    __shared__ int gbase[512];
    __shared__ int img[MS_TILE];
    __shared__ int tgt[MS_TILE];
    int tid = threadIdx.x;
    for (int tbase = blockIdx.x * MS_TILE; tbase < E; tbase += gridDim.x * MS_TILE) {
        int m = min(MS_TILE, E - tbase);
        for (int i = tid; i < 512; i += 256) cnt[i] = 0;
        __syncthreads();
        int pk[8], bk[8], rk[8];
        int nloc = 0;
        int j0 = tid * 8;
        if (j0 + 8 <= m) {
            int4 s0 = *(const int4*)(src + tbase + j0);
            int4 s1 = *(const int4*)(src + tbase + j0 + 4);
            int4 d0 = *(const int4*)(dst + tbase + j0);
            int4 d1 = *(const int4*)(dst + tbase + j0 + 4);
            int ss[8] = {s0.x, s0.y, s0.z, s0.w, s1.x, s1.y, s1.z, s1.w};
            int dd[8] = {d0.x, d0.y, d0.z, d0.w, d1.x, d1.y, d1.z, d1.w};
#pragma unroll
            for (int k = 0; k < 8; k++) {
                int b = dd[k] >> 8;
                pk[k] = (ss[k] << 8) | (dd[k] & 255);
                bk[k] = b;
                rk[k] = atomicAdd(&cnt[b], 1);
            }
            nloc = 8;
        } else {
            for (int j = j0; j < m; j++) {
                int s = src[tbase + j], d = dst[tbase + j];
                int b = d >> 8;
                pk[nloc] = (s << 8) | (d & 255);
                bk[nloc] = b;
                rk[nloc] = atomicAdd(&cnt[b], 1);
                nloc++;
            }
        }
        __syncthreads();
        // exclusive scan of cnt[0..512) by wave 0 (64 lanes x 8 serial)
        if (tid < 64) {
            int base = tid * 8;
            int vals[8];
            int s0 = 0;
#pragma unroll
            for (int j = 0; j < 8; j++) { vals[j] = cnt[base + j]; s0 += vals[j]; }
            int sc = s0;
#pragma unroll
            for (int o = 1; o < 64; o <<= 1) {
                int u = __shfl_up(sc, o);
                if (tid >= o) sc += u;
            }
            int ex = sc - s0;
#pragma unroll
            for (int j = 0; j < 8; j++) { off[base + j] = ex; ex += vals[j]; }
        }
        __syncthreads();
        // reserve slab space per bucket (one atomic per WG per nonempty bucket)
        for (int b = tid; b < 512; b += 256) {
            int c = cnt[b];
            gbase[b] = c ? (b * SLAB_CAP + atomicAdd(&gcur[b], c)) : 0;
        }
        __syncthreads();
        // scatter into LDS, grouped by bucket
        for (int i = 0; i < nloc; i++) {
            int p = off[bk[i]] + rk[i];
            img[p] = pk[i];
            tgt[p] = gbase[bk[i]] + rk[i];
        }
        __syncthreads();
        // coalesced write-out (consecutive slots -> consecutive targets per bucket run)
        for (int j = tid; j < m; j += 256) part[tgt[j]] = img[j];
        __syncthreads();
    }
}

// ---------------- scan slab fill counts -> CSR bases ----------------
__global__ __launch_bounds__(512) void scan_bases(const int* __restrict__ gcur,
                                                  int* __restrict__ bases, int m) {
    __shared__ int lds[512];
    int tid = threadIdx.x;
    int v = (tid < m) ? gcur[tid] : 0;
    lds[tid] = v;
    __syncthreads();
    for (int off = 1; off < 512; off <<= 1) {
        int x = (tid >= off) ? lds[tid - off] : 0;
        __syncthreads();
        lds[tid] += x;
        __syncthreads();
    }
    if (tid <= m) bases[tid] = lds[tid] - v;   // exclusive; bases[m] == E
}

// ------- bucket_place: per-node rowptr/dinv/CSR from the bucket's slab ----------
// csr entries are pre-shifted dword row offsets (s*32) for aggregate.
__global__ __launch_bounds__(256) void bucket_place(const int* __restrict__ gcur,
                                                    const int* __restrict__ bases,
                                                    const int* __restrict__ part,
                                                    int* __restrict__ rowptr,
                                                    int* __restrict__ csr,
                                                    float* __restrict__ dinv, int n) {
    __shared__ int cnt[256];
    __shared__ int cur[256];
    __shared__ int lds[256];
    __shared__ int img[SLAB_CAP];
    int b = blockIdx.x;
    int tid = threadIdx.x;
    int node0 = b << 8;
    int m = gcur[b];
    if (m > SLAB_CAP) m = SLAB_CAP;   // never in practice
    int base = bases[b];
    const int* slab = part + b * SLAB_CAP;
    cnt[tid] = 0;
    __syncthreads();
    for (int j = tid; j < m; j += 256) atomicAdd(&cnt[slab[j] & 255], 1);
    __syncthreads();
    int v = cnt[tid];
    lds[tid] = v;
    __syncthreads();
    for (int off = 1; off < 256; off <<= 1) {
        int x = (tid >= off) ? lds[tid - off] : 0;
        __syncthreads();
        lds[tid] += x;
        __syncthreads();
    }
    int ex = lds[tid] - v;   // exclusive within bucket
    cur[tid] = ex;
    int node = node0 + tid;
    if (node <= n) rowptr[node] = base + ex;   // last bucket's tid==n-node0 writes rowptr[n]=E
    if (node < n) dinv[node] = rsqrtf((float)(v + 1));  // +1 = self loop
    __syncthreads();
    for (int j = tid; j < m; j += 256) {
        int pkv = slab[j];
        int p = atomicAdd(&cur[pkv & 255], 1);
        img[p] = (pkv >> 8) << 5;   // dword offset of src row in t
    }
    __syncthreads();
    for (int j = tid; j < m; j += 256) csr[base + j] = img[j];  // coalesced
}

// ---- GEMM + dinv prescale: out[r] = bf16(dinv[r] * (A[r] @ W)), MFMA 16x16x32 ----
template <bool AF32>
__global__ __launch_bounds__(256) void gemm64(const void* __restrict__ A_,
                                              const float* __restrict__ W,
                                              const float* __restrict__ dinv,
                                              bf16s* __restrict__ out, int nrows) {
    int lane = threadIdx.x & 63;
    int wid = (blockIdx.x * blockDim.x + threadIdx.x) >> 6;
    int nwaves = (gridDim.x * blockDim.x) >> 6;
    int r = lane & 15;       // col-in-tile
    int q = lane >> 4;       // quad
    int kb = q * 8;

    // B fragments: 4 n-tiles x 2 k-halves. B[k][n]: n=lane&15, k=quad*8+j
    bf16x8 bfrag[4][2];
#pragma unroll
    for (int t = 0; t < 4; t++) {
#pragma unroll
        for (int h = 0; h < 2; h++) {
            bf16x8 bb;
            int ncol = t * 16 + r;
            int k0 = h * 32 + kb;
#pragma unroll
            for (int j = 0; j < 8; j++) bb[j] = (__bf16)W[(k0 + j) * 64 + ncol];
            bfrag[t][h] = bb;
        }
    }

    int ntiles = nrows >> 4;
    for (int tile = wid; tile < ntiles; tile += nwaves) {
        bf16x8 a0, a1;
        if (AF32) {
            const float* ap = (const float*)A_ + (size_t)(tile * 16 + r) * 64 + kb;
            f32x4 v0 = *reinterpret_cast<const f32x4*>(ap);
            f32x4 v1 = *reinterpret_cast<const f32x4*>(ap + 4);
            f32x4 v2 = *reinterpret_cast<const f32x4*>(ap + 32);
            f32x4 v3 = *reinterpret_cast<const f32x4*>(ap + 36);
#pragma unroll
            for (int j = 0; j < 4; j++) {
                a0[j] = (__bf16)v0[j]; a0[4 + j] = (__bf16)v1[j];
                a1[j] = (__bf16)v2[j]; a1[4 + j] = (__bf16)v3[j];
            }
        } else {
            const __bf16* ap = (const __bf16*)A_ + (size_t)(tile * 16 + r) * 64 + kb;
            a0 = *reinterpret_cast<const bf16x8*>(ap);
            a1 = *reinterpret_cast<const bf16x8*>(ap + 32);
        }
        f32x4 c[4];
#pragma unroll
        for (int t = 0; t < 4; t++) {
            f32x4 acc = {0.f, 0.f, 0.f, 0.f};
            acc = __builtin_amdgcn_mfma_f32_16x16x32_bf16(a0, bfrag[t][0], acc, 0, 0, 0);
            acc = __builtin_amdgcn_mfma_f32_16x16x32_bf16(a1, bfrag[t][1], acc, 0, 0, 0);
            c[t] = acc;
        }
        // C/D layout: col = lane&15, row = quad*4 + reg
        float dr[4];
#pragma unroll
        for (int g = 0; g < 4; g++) dr[g] = dinv[tile * 16 + q * 4 + g];
#pragma unroll
        for (int t = 0; t < 4; t++) {
#pragma unroll
            for (int g = 0; g < 4; g++) {
                int row = tile * 16 + q * 4 + g;
                out[(size_t)row * 64 + t * 16 + r] = __float2bfloat16(c[t][g] * dr[g]);
            }
        }
    }
}

// ---------------- aggregate: one wave per node; lane = (half, feature-pair) ----------
// Half h processes edges j+h; lane covers 2 features via dword gathers.
// t is pre-scaled by dinv[src]: out = relu(dinv[v] * (sum_e t[s] + t[v]) + bias)
template <bool OUTF32>
__global__ __launch_bounds__(256) void aggregate(const bf16s* __restrict__ t,
                                                 const float* __restrict__ dinv,
                                                 const int* __restrict__ rowptr,
                                                 const int* __restrict__ csr,
                                                 const float* __restrict__ bias,
                                                 void* __restrict__ out_, int n) {
    int gid = blockIdx.x * blockDim.x + threadIdx.x;
    int v = gid >> 6;
    if (v >= n) return;
    int lane = gid & 63;
    int half = lane >> 5;
    int c = lane & 31;                 // features 2c, 2c+1
    const unsigned* trow = (const unsigned*)t;
    unsigned sw = trow[(size_t)v * 32 + c];   // self-loop row (both halves broadcast-load)
    float ax, ay;
    if (half == 0) {
        ax = __uint_as_float(sw << 16);
        ay = __uint_as_float(sw & 0xffff0000u);
    } else {
        ax = 0.f; ay = 0.f;
    }
    int beg = rowptr[v], end = rowptr[v + 1];
    for (int j = beg; j < end; j += 16) {      // 16 edges per iter (8 per half)
        int idx[8];
        float wgt[8];
#pragma unroll
        for (int k = 0; k < 8; k++) {
            int jj = j + 2 * k + half;
            bool ok = jj < end;
            idx[k] = csr[ok ? jj : beg];       // pre-shifted dword row offset
            wgt[k] = ok ? 1.f : 0.f;
        }
        unsigned w[8];
#pragma unroll
        for (int k = 0; k < 8; k++) w[k] = trow[idx[k] + c];
#pragma unroll
        for (int k = 0; k < 8; k++) {
            ax = fmaf(wgt[k], __uint_as_float(w[k] << 16), ax);
            ay = fmaf(wgt[k], __uint_as_float(w[k] & 0xffff0000u), ay);
        }
    }
    ax += __shfl_xor(ax, 32);   // combine the two halves
    ay += __shfl_xor(ay, 32);
    if (half == 0) {
        float dv = dinv[v];
        float2 bb = ((const float2*)bias)[c];
        float ox = fmaxf(fmaf(dv, ax, bb.x), 0.f);
        float oy = fmaxf(fmaf(dv, ay, bb.y), 0.f);
        if (OUTF32) {
            float2 o2; o2.x = ox; o2.y = oy;
            ((float2*)out_)[(size_t)v * 32 + c] = o2;
        } else {
            unsigned ua = __float_as_uint(ox);
            unsigned ub = __float_as_uint(oy);
            ua = (ua + 0x7fffu + ((ua >> 16) & 1u)) >> 16;          // RNE bf16
            ub = (ub + 0x7fffu + ((ub >> 16) & 1u));
            ((unsigned*)out_)[(size_t)v * 32 + c] = (ua & 0xffffu) | (ub & 0xffff0000u);
        }
    }
}

extern "C" void kernel_launch(void* const* d_in, const int* in_sizes, int n_in,
                              void* d_out, int out_size, void* d_ws, size_t ws_size,
                              hipStream_t stream) {
    const float* x  = (const float*)d_in[0];
    const int*   ei = (const int*)d_in[1];
    const float* W1 = (const float*)d_in[2];
    const float* b1 = (const float*)d_in[3];
    const float* W2 = (const float*)d_in[4];
    const float* b2 = (const float*)d_in[5];
    float* out = (float*)d_out;

    int n = in_sizes[0] / 64;   // 100000
    int E = in_sizes[1] / 2;    // 1600000
    const int* src = ei;
    const int* dst = ei + E;
    int nbuck = (n + 255) >> 8; // 391

    // workspace carve
    char* w = (char*)d_ws;
    auto alloc = [&](size_t bytes) -> void* {
        void* p = (void*)w;
        w += (bytes + 255) & ~(size_t)255;
        return p;
    };
    int*   gcur   = (int*)alloc(2048);
    int*   bases  = (int*)alloc(2048);
    int*   rowptr = (int*)alloc((size_t)(n + 1) * 4);
    int*   csr    = (int*)alloc((size_t)E * 4);
    float* dinv   = (float*)alloc((size_t)n * 4);
    // overlay: slab part (nbuck*SLAB_CAP ints) shares space with tbuf (n*64 bf16) —
    // part is dead after bucket_place, before the first gemm writes tbuf.
    size_t slab_bytes = (size_t)nbuck * SLAB_CAP * 4;
    size_t tbuf_bytes = (size_t)n * 64 * 2;
    char*  ovl    = (char*)alloc(slab_bytes > tbuf_bytes ? slab_bytes : tbuf_bytes);
    int*   part   = (int*)ovl;
    bf16s* tbuf   = (bf16s*)ovl;
    bf16s* h1     = (bf16s*)alloc((size_t)n * 64 * 2);

    hipMemsetAsync(gcur, 0, 2048, stream);

    int ntiles = (E + MS_TILE - 1) / MS_TILE;   // 782
    multisplit<<<ntiles, 256, 0, stream>>>(src, dst, gcur, part, E);
    scan_bases<<<1, 512, 0, stream>>>(gcur, bases, nbuck);
    bucket_place<<<nbuck, 256, 0, stream>>>(gcur, bases, part, rowptr, csr, dinv, n);

    // layer 1: t = bf16(dinv .* (x @ W1)); h1 = relu(aggregate) in bf16
    gemm64<true><<<256, 256, 0, stream>>>(x, W1, dinv, tbuf, n);
    aggregate<false><<<(n * 64 + 255) / 256, 256, 0, stream>>>(tbuf, dinv, rowptr, csr, b1, h1, n);
    // layer 2: t = bf16(dinv .* (h1 @ W2)); out = relu(aggregate) in fp32
    gemm64<false><<<256, 256, 0, stream>>>(h1, W2, dinv, tbuf, n);
    aggregate<true><<<(n * 64 + 255) / 256, 256, 0, stream>>>(tbuf, dinv, rowptr, csr, b2, out, n);
}